// Round 7
// baseline (1429.111 us; speedup 1.0000x reference)
//
#include <hip/hip_runtime.h>
#include <hip/hip_fp16.h>

// ---------------------------------------------------------------------------
// Bidirectional 5-layer LSTM decoder, B=1024, H=32, T=200, feedback y->x.
// Round 7 = round 6 with the LDS CAPACITY BUG fixed:
//   layers 1-3 = 6 (l,d) slices x 1536 uint4 = 9216 uint4 = 144 KB (round 6
//   allocated/preloaded only 4608 -> layer2/d1 and layer3 read garbage).
//   dyn LDS = 147456 B weights + 3072 B activations = 150528 B (<160 KiB/CU,
//   1 block/CU as before).
//   layer 0 -> VGPRs (18 uint4/lane)        layer 4 -> VGPRs (48 uint4/lane)
//   per-timestep global traffic: ZERO.
//   activations: LDS 32-bit words (TBAA lesson r4), broadcast uint4 reads,
//   even-lane packed stores, compiler fence; no barriers in the t-loop (r5).
// Weight layout WT[l][d][k2][u][g][2] f16 (prep kernel verified rounds 2-5).
// ---------------------------------------------------------------------------

#define T_STEPS 200
#define BATCH 1024

#define W_ELEMS     107520            // f16 packed weights
#define BIAS_OFF_B  215040            // 1280 floats [l][d][u][g]
#define WLIN_OFF_B  220160            // 192 floats [3][64]
#define BLIN_OFF_B  220928            // 3 floats
#define START_OFF_B 220940            // 3 floats

typedef _Float16 h2 __attribute__((ext_vector_type(2)));

__global__ __launch_bounds__(256) void prep_kernel(
    const float* __restrict__ Wih0, const float* __restrict__ Whh0,
    const float* __restrict__ bih0, const float* __restrict__ bhh0,
    const float* __restrict__ Wih,  const float* __restrict__ Whh,
    const float* __restrict__ bih,  const float* __restrict__ bhh,
    const float* __restrict__ Wlin, const float* __restrict__ blin,
    const float* __restrict__ stok, char* __restrict__ ws)
{
    int i = blockIdx.x * 256 + threadIdx.x;
    _Float16* Wo = (_Float16*)ws;
    float* biasf  = (float*)(ws + BIAS_OFF_B);
    float* wlinf  = (float*)(ws + WLIN_OFF_B);
    float* blinf  = (float*)(ws + BLIN_OFF_B);
    float* startf = (float*)(ws + START_OFF_B);

    if (i < W_ELEMS) {
        int l, d, r, Kx;
        if (i < 9216) { l = 0; d = i / 4608; r = i % 4608; Kx = 4; }  // K0 = 4(pad:3+1) + 32
        else {
            int e = i - 9216;
            l = 1 + e / 24576;
            int r2 = e % 24576;
            d = r2 / 12288; r = r2 % 12288; Kx = 64;                   // K = 64 + 32
        }
        int k2 = r >> 8;            // 256 elems per k-pair block (32u * 4g * 2)
        int q  = r & 255;
        int u  = q >> 3;
        int g  = (q >> 1) & 3;
        int p  = q & 1;
        int k  = k2 * 2 + p;
        int gr = g * 32 + u;        // gate row in 4H (torch order i,f,g,o)
        float v = 0.f;
        if (k < Kx) {
            if (l == 0) { if (k < 3) v = Wih0[(d * 128 + gr) * 3 + k]; }
            else        v = Wih[(((l - 1) * 2 + d) * 128 + gr) * 64 + k];
        } else {
            int kh = k - Kx;
            if (l == 0) v = Whh0[(d * 128 + gr) * 32 + kh];
            else        v = Whh[(((l - 1) * 2 + d) * 128 + gr) * 32 + kh];
        }
        Wo[i] = (_Float16)v;
    } else if (i < W_ELEMS + 1280) {
        int b = i - W_ELEMS;                 // [l*2+d][u][g]
        int ld = b / 128; int rem = b % 128;
        int u = rem / 4;  int g = rem % 4;
        int gr = g * 32 + u;
        float v;
        if (ld < 2) v = bih0[ld * 128 + gr] + bhh0[ld * 128 + gr];
        else        v = bih[(ld - 2) * 128 + gr] + bhh[(ld - 2) * 128 + gr];
        biasf[b] = v;
    } else if (i < W_ELEMS + 1280 + 192) {
        wlinf[i - (W_ELEMS + 1280)] = Wlin[i - (W_ELEMS + 1280)];
    } else if (i < W_ELEMS + 1280 + 192 + 3) {
        blinf[i - (W_ELEMS + 1280 + 192)] = blin[i - (W_ELEMS + 1280 + 192)];
    } else if (i < W_ELEMS + 1280 + 192 + 6) {
        startf[i - (W_ELEMS + 1280 + 192 + 3)] = stok[i - (W_ELEMS + 1280 + 192 + 3)];
    }
}

__device__ __forceinline__ float sigm(float x)  { return 1.f / (1.f + __expf(-x)); }
__device__ __forceinline__ float tanhx(float x) { return 2.f * sigm(2.f * x) - 1.f; }
__device__ __forceinline__ h2 as_h2(unsigned v) { return __builtin_bit_cast(h2, v); }

__device__ __forceinline__ float fdot2f(h2 a, h2 b, float c) {
#if __has_builtin(__builtin_amdgcn_fdot2)
    return __builtin_amdgcn_fdot2(a, b, c, false);
#else
    return fmaf((float)a.x, (float)b.x, fmaf((float)a.y, (float)b.y, c));
#endif
}

__device__ __forceinline__ unsigned short f2h_bits(float x) {
    return __builtin_bit_cast(unsigned short, (_Float16)x);
}
__device__ __forceinline__ unsigned packh2(float lo, float hi) {
    return (unsigned)f2h_bits(lo) | ((unsigned)f2h_bits(hi) << 16);
}
// component c (0..3) of a uint4 held in registers; folds to a register pick
// when c is a compile-time constant (all uses are inside #pragma unroll).
__device__ __forceinline__ unsigned u4c(const uint4& v, int c) {
    return c == 0 ? v.x : (c == 1 ? v.y : (c == 2 ? v.z : v.w));
}

#define DOT4(WV, XV)                                  \
    acc.x = fdot2f(as_h2((WV).x), (XV), acc.x);       \
    acc.y = fdot2f(as_h2((WV).y), (XV), acc.y);       \
    acc.z = fdot2f(as_h2((WV).z), (XV), acc.z);       \
    acc.w = fdot2f(as_h2((WV).w), (XV), acc.w);

extern __shared__ uint4 smem[];   // [0,9216): layers1-3 weights; then act words

__global__ __launch_bounds__(256, 1) void lstm_kernel(
    const char* __restrict__ ws,
    const float* __restrict__ h0,
    const float* __restrict__ c0,
    float* __restrict__ out)
{
    const int tid  = threadIdx.x;
    const int w    = tid >> 6;          // wave in block (0..3) = row slot
    const int lane = tid & 63;
    const int d    = lane >> 5;
    const int u    = lane & 31;
    const int row  = blockIdx.x * 4 + w;

    // activation words after the weight region (9216 uint4)
    unsigned* aw  = (unsigned*)(smem + 9216);
    unsigned* xw  = aw + w * 32;                 // layer input, 64 f16 / 32 words
    unsigned* hw0 = aw + 128;                    // hw[l][w][32]
#define HW(l) (hw0 + ((l) * 4 + w) * 32)

    const uint4* gw = (const uint4*)ws;

    // ---- cooperative preload of layers 1-3 weights into LDS (once) ----
    for (int i = tid; i < 9216; i += 256) smem[i] = gw[1152 + i];

    const float* biasf  = (const float*)(ws + BIAS_OFF_B);
    const float* wlinf  = (const float*)(ws + WLIN_OFF_B);
    const float* blinf  = (const float*)(ws + BLIN_OFF_B);
    const float* startf = (const float*)(ws + START_OFF_B);

    // ---- layer-0 (18) + layer-4 (48) weights into registers ----
    const uint4* wp0 = gw + d * 576 + u;
    uint4 w0r[18];
#pragma unroll
    for (int j = 0; j < 18; j++) w0r[j] = wp0[j * 32];
    const uint4* wp4 = gw + 1152 + (3 * 2 + d) * 1536 + u;
    uint4 w4r[48];
#pragma unroll
    for (int j = 0; j < 48; j++) w4r[j] = wp4[j * 32];

    float cs[5];
#pragma unroll
    for (int l = 0; l < 5; l++) {
        int idx = ((2 * l + d) * BATCH + row) * 32 + u;
        cs[l] = c0[idx];
        float hv = h0[idx];
        float hp_ = __shfl_xor(hv, 1);
        if (!(lane & 1)) HW(l)[lane >> 1] = packh2(hv, hp_);
    }
    float4 bias4[5];
#pragma unroll
    for (int l = 0; l < 5; l++)
        bias4[l] = *(const float4*)(biasf + ((l * 2 + d) * 32 + u) * 4);

    const float wl0 = wlinf[lane], wl1 = wlinf[64 + lane], wl2 = wlinf[128 + lane];
    const float bl0 = blinf[0], bl1 = blinf[1], bl2 = blinf[2];
    float y0 = startf[0], y1 = startf[1], y2 = startf[2];

    __syncthreads();    // preload fence (only barrier in the kernel)

#define STORE_H(LBUF, STORE_X, V)                                   \
    {                                                               \
        float _p = __shfl_xor((V), 1);                              \
        unsigned _pk = packh2((V), _p);                             \
        if (!(lane & 1)) {                                          \
            (LBUF)[lane >> 1] = _pk;                                \
            if (STORE_X) xw[lane >> 1] = _pk;                       \
        }                                                           \
    }                                                               \
    __asm__ volatile("" ::: "memory");

    for (int t = 0; t < T_STEPS; t++) {
        // ----- layer 0: weights in registers, h via 4 broadcast b128 -----
        {
            float4 acc = bias4[0];
            h2 y01; y01.x = (_Float16)y0; y01.y = (_Float16)y1;
            h2 y2p; y2p.x = (_Float16)y2; y2p.y = (_Float16)0.f;
            DOT4(w0r[0], y01);
            DOT4(w0r[1], y2p);
            uint4 hq[4];
#pragma unroll
            for (int q = 0; q < 4; q++)
                hq[q] = *(const uint4*)(HW(0) + d * 16 + q * 4);
#pragma unroll
            for (int c = 0; c < 16; c++) {
                h2 hx = as_h2(u4c(hq[c >> 2], c & 3));
                DOT4(w0r[2 + c], hx);
            }
            float ii = sigm(acc.x), ff = sigm(acc.y), gg = tanhx(acc.z), oo = sigm(acc.w);
            cs[0] = ff * cs[0] + ii * gg;
            float h = oo * tanhx(cs[0]);
            STORE_H(HW(0), 1, h);
        }

        // ----- layers 1-3: weights in LDS -----
#pragma unroll
        for (int l = 1; l <= 3; l++) {
            float4 acc = bias4[l];
            const uint4* lw = smem + ((l - 1) * 2 + d) * 1536 + u;
            uint4 xq[8];
#pragma unroll
            for (int q = 0; q < 8; q++) xq[q] = *(const uint4*)(xw + q * 4);
            uint4 hq[4];
#pragma unroll
            for (int q = 0; q < 4; q++)
                hq[q] = *(const uint4*)(HW(l) + d * 16 + q * 4);
#pragma unroll
            for (int c = 0; c < 32; c++) {
                uint4 wv = lw[c * 32];
                h2 xv = as_h2(u4c(xq[c >> 2], c & 3));
                DOT4(wv, xv);
            }
#pragma unroll
            for (int c = 0; c < 16; c++) {
                uint4 wv = lw[(32 + c) * 32];
                h2 hx = as_h2(u4c(hq[c >> 2], c & 3));
                DOT4(wv, hx);
            }
            float ii = sigm(acc.x), ff = sigm(acc.y), gg = tanhx(acc.z), oo = sigm(acc.w);
            cs[l] = ff * cs[l] + ii * gg;
            float h = oo * tanhx(cs[l]);
            STORE_H(HW(l), 1, h);
        }

        // ----- layer 4: weights in registers -----
        float h4;
        {
            float4 acc = bias4[4];
            uint4 xq[8];
#pragma unroll
            for (int q = 0; q < 8; q++) xq[q] = *(const uint4*)(xw + q * 4);
            uint4 hq[4];
#pragma unroll
            for (int q = 0; q < 4; q++)
                hq[q] = *(const uint4*)(HW(4) + d * 16 + q * 4);
#pragma unroll
            for (int c = 0; c < 32; c++) {
                h2 xv = as_h2(u4c(xq[c >> 2], c & 3));
                DOT4(w4r[c], xv);
            }
#pragma unroll
            for (int c = 0; c < 16; c++) {
                h2 hx = as_h2(u4c(hq[c >> 2], c & 3));
                DOT4(w4r[32 + c], hx);
            }
            float ii = sigm(acc.x), ff = sigm(acc.y), gg = tanhx(acc.z), oo = sigm(acc.w);
            cs[4] = ff * cs[4] + ii * gg;
            h4 = oo * tanhx(cs[4]);
            STORE_H(HW(4), 0, h4);
        }

        // ----- output linear + tanh + feedback (concat = h4 per lane) -----
        {
            float p0 = h4 * wl0, p1 = h4 * wl1, p2 = h4 * wl2;
#pragma unroll
            for (int off = 32; off >= 1; off >>= 1) {
                p0 += __shfl_xor(p0, off);
                p1 += __shfl_xor(p1, off);
                p2 += __shfl_xor(p2, off);
            }
            y0 = tanhx(p0 + bl0);
            y1 = tanhx(p1 + bl1);
            y2 = tanhx(p2 + bl2);
            if (lane < 3) {
                float yv = (lane == 0) ? y0 : (lane == 1 ? y1 : y2);
                out[(t * BATCH + row) * 3 + lane] = yv;
            }
        }
    }
#undef STORE_H
#undef HW
}

extern "C" void kernel_launch(void* const* d_in, const int* in_sizes, int n_in,
                              void* d_out, int out_size, void* d_ws, size_t ws_size,
                              hipStream_t stream)
{
    const float* h0   = (const float*)d_in[0];
    const float* c0   = (const float*)d_in[1];
    const float* stok = (const float*)d_in[2];
    const float* Wih0 = (const float*)d_in[3];
    const float* Whh0 = (const float*)d_in[4];
    const float* bih0 = (const float*)d_in[5];
    const float* bhh0 = (const float*)d_in[6];
    const float* Wih  = (const float*)d_in[7];
    const float* Whh  = (const float*)d_in[8];
    const float* bih  = (const float*)d_in[9];
    const float* bhh  = (const float*)d_in[10];
    const float* Wlin = (const float*)d_in[11];
    const float* blin = (const float*)d_in[12];

    prep_kernel<<<426, 256, 0, stream>>>(Wih0, Whh0, bih0, bhh0, Wih, Whh,
                                         bih, bhh, Wlin, blin, stok, (char*)d_ws);

    // layers1-3 weights 147456 B + activation words (128 + 640)*4 = 150528 B
    const int dyn_lds = 9216 * 16 + 3072;
    (void)hipFuncSetAttribute((const void*)lstm_kernel,
                              hipFuncAttributeMaxDynamicSharedMemorySize, dyn_lds);
    lstm_kernel<<<256, 256, dyn_lds, stream>>>((const char*)d_ws, h0, c0,
                                               (float*)d_out);
}

// Round 8
// 1102.291 us; speedup vs baseline: 1.2965x; 1.2965x over previous
//
#include <hip/hip_runtime.h>
#include <hip/hip_fp16.h>

// ---------------------------------------------------------------------------
// Bidirectional 5-layer LSTM decoder, B=1024, H=32, T=200, feedback y->x.
// Round 8 = round 7 + FORCED layer-4 residency:
//   Round-7 counters (VGPR_Count=184) proved the compiler rematerialized the
//   48 global_load_dwordx4 of layer-4 weights inside the t-loop instead of
//   keeping them in registers. Fix: park the 192 dwords in AGPRs via inline
//   asm (v_accvgpr_write_b32 pre-loop, volatile v_accvgpr_read_b32 per use)
//   -> remat impossible (producer is opaque asm), LICM blocked (volatile).
//   layer 0 -> VGPRs (compiler kept these)   layer 4 -> AGPRs (forced)
//   layers 1-3 -> LDS 144 KB                 per-ts global traffic: ZERO
//   Also removed the xw duplicate buffer: layer l reads x from HW(l-1).
// Weight layout WT[l][d][k2][u][g][2] f16 (prep kernel verified rounds 2-7).
// ---------------------------------------------------------------------------

#define T_STEPS 200
#define BATCH 1024

#define W_ELEMS     107520            // f16 packed weights
#define BIAS_OFF_B  215040            // 1280 floats [l][d][u][g]
#define WLIN_OFF_B  220160            // 192 floats [3][64]
#define BLIN_OFF_B  220928            // 3 floats
#define START_OFF_B 220940            // 3 floats

typedef _Float16 h2 __attribute__((ext_vector_type(2)));

__global__ __launch_bounds__(256) void prep_kernel(
    const float* __restrict__ Wih0, const float* __restrict__ Whh0,
    const float* __restrict__ bih0, const float* __restrict__ bhh0,
    const float* __restrict__ Wih,  const float* __restrict__ Whh,
    const float* __restrict__ bih,  const float* __restrict__ bhh,
    const float* __restrict__ Wlin, const float* __restrict__ blin,
    const float* __restrict__ stok, char* __restrict__ ws)
{
    int i = blockIdx.x * 256 + threadIdx.x;
    _Float16* Wo = (_Float16*)ws;
    float* biasf  = (float*)(ws + BIAS_OFF_B);
    float* wlinf  = (float*)(ws + WLIN_OFF_B);
    float* blinf  = (float*)(ws + BLIN_OFF_B);
    float* startf = (float*)(ws + START_OFF_B);

    if (i < W_ELEMS) {
        int l, d, r, Kx;
        if (i < 9216) { l = 0; d = i / 4608; r = i % 4608; Kx = 4; }  // K0 = 4(pad:3+1) + 32
        else {
            int e = i - 9216;
            l = 1 + e / 24576;
            int r2 = e % 24576;
            d = r2 / 12288; r = r2 % 12288; Kx = 64;                   // K = 64 + 32
        }
        int k2 = r >> 8;            // 256 elems per k-pair block (32u * 4g * 2)
        int q  = r & 255;
        int u  = q >> 3;
        int g  = (q >> 1) & 3;
        int p  = q & 1;
        int k  = k2 * 2 + p;
        int gr = g * 32 + u;        // gate row in 4H (torch order i,f,g,o)
        float v = 0.f;
        if (k < Kx) {
            if (l == 0) { if (k < 3) v = Wih0[(d * 128 + gr) * 3 + k]; }
            else        v = Wih[(((l - 1) * 2 + d) * 128 + gr) * 64 + k];
        } else {
            int kh = k - Kx;
            if (l == 0) v = Whh0[(d * 128 + gr) * 32 + kh];
            else        v = Whh[(((l - 1) * 2 + d) * 128 + gr) * 32 + kh];
        }
        Wo[i] = (_Float16)v;
    } else if (i < W_ELEMS + 1280) {
        int b = i - W_ELEMS;                 // [l*2+d][u][g]
        int ld = b / 128; int rem = b % 128;
        int u = rem / 4;  int g = rem % 4;
        int gr = g * 32 + u;
        float v;
        if (ld < 2) v = bih0[ld * 128 + gr] + bhh0[ld * 128 + gr];
        else        v = bih[(ld - 2) * 128 + gr] + bhh[(ld - 2) * 128 + gr];
        biasf[b] = v;
    } else if (i < W_ELEMS + 1280 + 192) {
        wlinf[i - (W_ELEMS + 1280)] = Wlin[i - (W_ELEMS + 1280)];
    } else if (i < W_ELEMS + 1280 + 192 + 3) {
        blinf[i - (W_ELEMS + 1280 + 192)] = blin[i - (W_ELEMS + 1280 + 192)];
    } else if (i < W_ELEMS + 1280 + 192 + 6) {
        startf[i - (W_ELEMS + 1280 + 192 + 3)] = stok[i - (W_ELEMS + 1280 + 192 + 3)];
    }
}

__device__ __forceinline__ float sigm(float x)  { return 1.f / (1.f + __expf(-x)); }
__device__ __forceinline__ float tanhx(float x) { return 2.f * sigm(2.f * x) - 1.f; }
__device__ __forceinline__ h2 as_h2(unsigned v) { return __builtin_bit_cast(h2, v); }

__device__ __forceinline__ float fdot2f(h2 a, h2 b, float c) {
#if __has_builtin(__builtin_amdgcn_fdot2)
    return __builtin_amdgcn_fdot2(a, b, c, false);
#else
    return fmaf((float)a.x, (float)b.x, fmaf((float)a.y, (float)b.y, c));
#endif
}

__device__ __forceinline__ unsigned short f2h_bits(float x) {
    return __builtin_bit_cast(unsigned short, (_Float16)x);
}
__device__ __forceinline__ unsigned packh2(float lo, float hi) {
    return (unsigned)f2h_bits(lo) | ((unsigned)f2h_bits(hi) << 16);
}
__device__ __forceinline__ unsigned u4c(const uint4& v, int c) {
    return c == 0 ? v.x : (c == 1 ? v.y : (c == 2 ? v.z : v.w));
}

// ---- AGPR parking: producer is opaque asm -> no remat; reads volatile ->
// no LICM hoist back out of the t-loop. gfx950 unified file, full-rate moves.
__device__ __forceinline__ unsigned agpr_park(unsigned v) {
    unsigned r;
    __asm__ volatile("v_accvgpr_write_b32 %0, %1" : "=a"(r) : "v"(v));
    return r;
}
__device__ __forceinline__ unsigned agpr_get(const unsigned& a) {
    unsigned r;
    __asm__ volatile("v_accvgpr_read_b32 %0, %1" : "=v"(r) : "a"(a));
    return r;
}

#define DOT4(WV, XV)                                  \
    acc.x = fdot2f(as_h2((WV).x), (XV), acc.x);       \
    acc.y = fdot2f(as_h2((WV).y), (XV), acc.y);       \
    acc.z = fdot2f(as_h2((WV).z), (XV), acc.z);       \
    acc.w = fdot2f(as_h2((WV).w), (XV), acc.w);

extern __shared__ uint4 smem[];   // [0,9216): layers1-3 weights; then act words

__global__ __launch_bounds__(256, 1) void lstm_kernel(
    const char* __restrict__ ws,
    const float* __restrict__ h0,
    const float* __restrict__ c0,
    float* __restrict__ out)
{
    const int tid  = threadIdx.x;
    const int w    = tid >> 6;          // wave in block (0..3) = row slot
    const int lane = tid & 63;
    const int d    = lane >> 5;
    const int u    = lane & 31;
    const int row  = blockIdx.x * 4 + w;

    // activation words after the weight region: hw[l][w][32]
    unsigned* hw0 = (unsigned*)(smem + 9216);
#define HW(l) (hw0 + ((l) * 4 + w) * 32)

    const uint4* gw = (const uint4*)ws;

    // ---- cooperative preload of layers 1-3 weights into LDS (once) ----
    for (int i = tid; i < 9216; i += 256) smem[i] = gw[1152 + i];

    const float* biasf  = (const float*)(ws + BIAS_OFF_B);
    const float* wlinf  = (const float*)(ws + WLIN_OFF_B);
    const float* blinf  = (const float*)(ws + BLIN_OFF_B);
    const float* startf = (const float*)(ws + START_OFF_B);

    // ---- layer-0 weights -> VGPRs; layer-4 weights -> AGPRs (forced) ----
    const uint4* wp0 = gw + d * 576 + u;
    uint4 w0r[18];
#pragma unroll
    for (int j = 0; j < 18; j++) w0r[j] = wp0[j * 32];

    const uint4* wp4 = gw + 1152 + (3 * 2 + d) * 1536 + u;
    unsigned w4a[192];
#pragma unroll
    for (int j = 0; j < 48; j++) {
        uint4 v = wp4[j * 32];
        w4a[4 * j + 0] = agpr_park(v.x);
        w4a[4 * j + 1] = agpr_park(v.y);
        w4a[4 * j + 2] = agpr_park(v.z);
        w4a[4 * j + 3] = agpr_park(v.w);
    }

    float cs[5];
#pragma unroll
    for (int l = 0; l < 5; l++) {
        int idx = ((2 * l + d) * BATCH + row) * 32 + u;
        cs[l] = c0[idx];
        float hv = h0[idx];
        float hp_ = __shfl_xor(hv, 1);
        if (!(lane & 1)) HW(l)[lane >> 1] = packh2(hv, hp_);
    }
    float4 bias4[5];
#pragma unroll
    for (int l = 0; l < 5; l++)
        bias4[l] = *(const float4*)(biasf + ((l * 2 + d) * 32 + u) * 4);

    const float wl0 = wlinf[lane], wl1 = wlinf[64 + lane], wl2 = wlinf[128 + lane];
    const float bl0 = blinf[0], bl1 = blinf[1], bl2 = blinf[2];
    float y0 = startf[0], y1 = startf[1], y2 = startf[2];

    __syncthreads();    // preload fence (only barrier in the kernel)

#define STORE_H(LBUF, V)                                            \
    {                                                               \
        float _p = __shfl_xor((V), 1);                              \
        if (!(lane & 1)) (LBUF)[lane >> 1] = packh2((V), _p);       \
    }                                                               \
    __asm__ volatile("" ::: "memory");

    for (int t = 0; t < T_STEPS; t++) {
        // ----- layer 0: weights in VGPRs, h via 4 broadcast b128 -----
        {
            float4 acc = bias4[0];
            h2 y01; y01.x = (_Float16)y0; y01.y = (_Float16)y1;
            h2 y2p; y2p.x = (_Float16)y2; y2p.y = (_Float16)0.f;
            DOT4(w0r[0], y01);
            DOT4(w0r[1], y2p);
            uint4 hq[4];
#pragma unroll
            for (int q = 0; q < 4; q++)
                hq[q] = *(const uint4*)(HW(0) + d * 16 + q * 4);
#pragma unroll
            for (int c = 0; c < 16; c++) {
                h2 hx = as_h2(u4c(hq[c >> 2], c & 3));
                DOT4(w0r[2 + c], hx);
            }
            float ii = sigm(acc.x), ff = sigm(acc.y), gg = tanhx(acc.z), oo = sigm(acc.w);
            cs[0] = ff * cs[0] + ii * gg;
            float h = oo * tanhx(cs[0]);
            STORE_H(HW(0), h);
        }

        // ----- layers 1-3: weights in LDS; x read from HW(l-1) -----
#pragma unroll
        for (int l = 1; l <= 3; l++) {
            float4 acc = bias4[l];
            const uint4* lw = smem + ((l - 1) * 2 + d) * 1536 + u;
            uint4 xq[8];
#pragma unroll
            for (int q = 0; q < 8; q++)
                xq[q] = *(const uint4*)(HW(l - 1) + q * 4);
            uint4 hq[4];
#pragma unroll
            for (int q = 0; q < 4; q++)
                hq[q] = *(const uint4*)(HW(l) + d * 16 + q * 4);
#pragma unroll
            for (int c = 0; c < 32; c++) {
                uint4 wv = lw[c * 32];
                h2 xv = as_h2(u4c(xq[c >> 2], c & 3));
                DOT4(wv, xv);
            }
#pragma unroll
            for (int c = 0; c < 16; c++) {
                uint4 wv = lw[(32 + c) * 32];
                h2 hx = as_h2(u4c(hq[c >> 2], c & 3));
                DOT4(wv, hx);
            }
            float ii = sigm(acc.x), ff = sigm(acc.y), gg = tanhx(acc.z), oo = sigm(acc.w);
            cs[l] = ff * cs[l] + ii * gg;
            float h = oo * tanhx(cs[l]);
            STORE_H(HW(l), h);
        }

        // ----- layer 4: weights read back from AGPRs -----
        float h4;
        {
            float4 acc = bias4[4];
            uint4 xq[8];
#pragma unroll
            for (int q = 0; q < 8; q++)
                xq[q] = *(const uint4*)(HW(3) + q * 4);
            uint4 hq[4];
#pragma unroll
            for (int q = 0; q < 4; q++)
                hq[q] = *(const uint4*)(HW(4) + d * 16 + q * 4);
#pragma unroll
            for (int c = 0; c < 32; c++) {
                uint4 wv;
                wv.x = agpr_get(w4a[4 * c + 0]);
                wv.y = agpr_get(w4a[4 * c + 1]);
                wv.z = agpr_get(w4a[4 * c + 2]);
                wv.w = agpr_get(w4a[4 * c + 3]);
                h2 xv = as_h2(u4c(xq[c >> 2], c & 3));
                DOT4(wv, xv);
            }
#pragma unroll
            for (int c = 0; c < 16; c++) {
                uint4 wv;
                wv.x = agpr_get(w4a[128 + 4 * c + 0]);
                wv.y = agpr_get(w4a[128 + 4 * c + 1]);
                wv.z = agpr_get(w4a[128 + 4 * c + 2]);
                wv.w = agpr_get(w4a[128 + 4 * c + 3]);
                h2 hx = as_h2(u4c(hq[c >> 2], c & 3));
                DOT4(wv, hx);
            }
            float ii = sigm(acc.x), ff = sigm(acc.y), gg = tanhx(acc.z), oo = sigm(acc.w);
            cs[4] = ff * cs[4] + ii * gg;
            h4 = oo * tanhx(cs[4]);
            STORE_H(HW(4), h4);
        }

        // ----- output linear + tanh + feedback (concat = h4 per lane) -----
        {
            float p0 = h4 * wl0, p1 = h4 * wl1, p2 = h4 * wl2;
#pragma unroll
            for (int off = 32; off >= 1; off >>= 1) {
                p0 += __shfl_xor(p0, off);
                p1 += __shfl_xor(p1, off);
                p2 += __shfl_xor(p2, off);
            }
            y0 = tanhx(p0 + bl0);
            y1 = tanhx(p1 + bl1);
            y2 = tanhx(p2 + bl2);
            if (lane < 3) {
                float yv = (lane == 0) ? y0 : (lane == 1 ? y1 : y2);
                out[(t * BATCH + row) * 3 + lane] = yv;
            }
        }
    }
#undef STORE_H
#undef HW
}

extern "C" void kernel_launch(void* const* d_in, const int* in_sizes, int n_in,
                              void* d_out, int out_size, void* d_ws, size_t ws_size,
                              hipStream_t stream)
{
    const float* h0   = (const float*)d_in[0];
    const float* c0   = (const float*)d_in[1];
    const float* stok = (const float*)d_in[2];
    const float* Wih0 = (const float*)d_in[3];
    const float* Whh0 = (const float*)d_in[4];
    const float* bih0 = (const float*)d_in[5];
    const float* bhh0 = (const float*)d_in[6];
    const float* Wih  = (const float*)d_in[7];
    const float* Whh  = (const float*)d_in[8];
    const float* bih  = (const float*)d_in[9];
    const float* bhh  = (const float*)d_in[10];
    const float* Wlin = (const float*)d_in[11];
    const float* blin = (const float*)d_in[12];

    prep_kernel<<<426, 256, 0, stream>>>(Wih0, Whh0, bih0, bhh0, Wih, Whh,
                                         bih, bhh, Wlin, blin, stok, (char*)d_ws);

    // layers1-3 weights 147456 B + activation words 640*4 = 150016 B
    const int dyn_lds = 9216 * 16 + 2560;
    (void)hipFuncSetAttribute((const void*)lstm_kernel,
                              hipFuncAttributeMaxDynamicSharedMemorySize, dyn_lds);
    lstm_kernel<<<256, 256, dyn_lds, stream>>>((const char*)d_ws, h0, c0,
                                               (float*)d_out);
}